// Round 6
// baseline (552.566 us; speedup 1.0000x reference)
//
#include <hip/hip_runtime.h>
#include <hip/hip_fp16.h>

// GCN 3-layer encoder for MI355X.
// dinv folded into H (Hs = dinv*h, fp16); EW packs (src<<15 | w_q15) in 4 B.
// Build: two-phase, 64-node partitions (p=dst>>6) so slot counters live in
// LDS (R4: killed the 1.6M global-RMW bottleneck; 450->436 us).
// R6: INSTRUMENTATION ROUND. R5 (1024-thr agg) regressed -> reverted to
// R4-exact everywhere. New: agg L0/L1 are each split into two COLUMN-HALF
// dispatches (c0=0/32 in half2 units; H rows are 2x128B lines so halves
// fetch disjoint lines -> no extra fabric bytes). Purpose: k_agg's 61us
// dispatches monopolized the duration-sorted top-5 profile; at ~33us the
// hidden middle kernels (bin/fill/gemm) surface, and adjacent same-iteration
// dispatches expose launch-gap size via timestamps. ~8us VALU penalty
// accepted for full pipeline visibility.
// k_pre(init+wprep) -> k_bin -> k_fill -> [gemm_mfma -> agg x2 halves] x3

typedef __attribute__((ext_vector_type(8))) _Float16 f16x8;
typedef __attribute__((ext_vector_type(4))) float f32x4;
typedef unsigned long long u64;

#define WQ_BITS 15
#define WQ_SCALE 32768.0f
#define WQ_MASK 32767u
#define MAXNP 2048

#define RL(v, k) __builtin_amdgcn_readlane((v), (k))

// Fused: zero tails + transpose W0/W1/W2 (fp32 [k][n]) into f16 Wt [n][k].
__global__ __launch_bounds__(256) void k_pre(int* tail, int NP,
                                             const float* __restrict__ W0,
                                             const float* __restrict__ W1,
                                             const float* __restrict__ W2,
                                             __half* __restrict__ wt0,
                                             __half* __restrict__ wt1,
                                             __half* __restrict__ wt2) {
    int id = blockIdx.x * 256 + threadIdx.x;
    if (id < NP) tail[id] = 0;
    if (id < 16384) {
        int n = id >> 7, k = id & 127;
        wt0[id] = __float2half(W0[k * 128 + n]);
    } else if (id < 32768) {
        int j = id - 16384, n = j >> 7, k = j & 127;
        wt1[j] = __float2half(W1[k * 128 + n]);
    } else if (id < 40960) {
        int j = id - 32768, n = j >> 7, k = j & 127;  // n in [0,64)
        wt2[j] = __float2half(W2[k * 64 + n]);
    }
}

// Phase 1: bin edges into NP per-node-range lists. Two passes over a
// contiguous per-block chunk (2nd pass L2-hot). Global atomics: one per
// (block, nonzero partition) -- ~390K over 1563 spread words.
__global__ __launch_bounds__(256) void k_bin(const int* __restrict__ src,
                                             const int* __restrict__ dst,
                                             const float* __restrict__ w,
                                             int* tail, u64* __restrict__ glist,
                                             int E, int ecap, int NP, int shift) {
    __shared__ unsigned int h[MAXNP];
    __shared__ int base[MAXNP];
    const int nb = gridDim.x;
    const int per = (E + nb - 1) / nb;
    const int e0 = blockIdx.x * per;
    const int e1 = (e0 + per < E) ? e0 + per : E;

    for (int i = threadIdx.x; i < NP; i += 256) h[i] = 0;
    __syncthreads();
    for (int e = e0 + (int)threadIdx.x; e < e1; e += 256) {
        int p = dst[e] >> shift;
        atomicAdd(&h[p], 1u);
    }
    __syncthreads();
    for (int i = threadIdx.x; i < NP; i += 256) {
        unsigned int c = h[i];
        base[i] = c ? atomicAdd(&tail[i], (int)c) : 0;
    }
    __syncthreads();
    for (int e = e0 + (int)threadIdx.x; e < e1; e += 256) {
        int t = dst[e];  // L2-hot (pass 1 cached it)
        int p = t >> shift;
        int s = __builtin_nontemporal_load(src + e);
        float we = __builtin_nontemporal_load(w + e);
        int wq = (int)(we * WQ_SCALE + 0.5f);
        wq = (wq < (int)WQ_MASK) ? wq : (int)WQ_MASK;
        u64 v = ((u64)(unsigned)t << 32) |
                ((unsigned)s << WQ_BITS) | (unsigned)wq;
        unsigned int idx = atomicSub(&h[p], 1u) - 1u;  // LDS, order-free
        int pos = base[p] + (int)idx;
        if (pos < ecap) glist[(size_t)p * ecap + pos] = v;
    }
}

// Phase 2: one block per partition (64-node range). Slot assignment via LDS
// atomics; EW plain stores into the partition's own L2-resident region.
// Also emits cnt (plain store) and dinv (LDS float accumulation of wq).
__global__ __launch_bounds__(256) void k_fill(const int* __restrict__ tail,
                                              const u64* __restrict__ glist,
                                              int ecap, int* __restrict__ cnt,
                                              float* __restrict__ dinv,
                                              unsigned int* __restrict__ EW,
                                              int cap, int N, int shift) {
    __shared__ unsigned int lcnt[MAXNP];
    __shared__ float lws[MAXNP];
    const int p = blockIdx.x;
    const int np = 1 << shift;
    const int t0 = p << shift;
    for (int i = threadIdx.x; i < np; i += 256) { lcnt[i] = 0; lws[i] = 0.f; }
    __syncthreads();
    int n = tail[p];
    if (n > ecap) n = ecap;
    const u64* L = glist + (size_t)p * ecap;
    for (int j = threadIdx.x; j < n; j += 256) {
        u64 v = L[j];
        int t = (int)(v >> 32);
        int loc = t - t0;
        unsigned int k = atomicAdd(&lcnt[loc], 1u);  // LDS
        if ((int)k < cap) {
            EW[(size_t)t * cap + k] = (unsigned int)v;
            atomicAdd(&lws[loc], (float)((unsigned int)v & WQ_MASK));  // LDS f32
        }
    }
    __syncthreads();
    for (int i = threadIdx.x; i < np; i += 256) {
        int t = t0 + i;
        if (t < N) {
            int c = (int)lcnt[i];
            c = (c < cap) ? c : cap;
            cnt[t] = c;
            dinv[t] = 1.0f / sqrtf(1.0f + lws[i] * (1.0f / WQ_SCALE));
        }
    }
}

// MFMA GEMM: H[N x BN] = dinv[r]*(X[N x 128] @ W[128 x BN]) as fp16.
// Per wave: 16 rows x BN cols. Operand swap: A:=W^T-frag (from Wt[n][k]),
// B:=X^T-frag -> each lane holds 4 consecutive H-cols -> 8 B stores. No LDS.
// dinv read from global (computed by k_fill).
template <int BN, bool XFP32>
__global__ __launch_bounds__(256, 4) void k_gemm(const void* __restrict__ Xv,
                                                 const __half* __restrict__ Wt,
                                                 const float* __restrict__ dinv,
                                                 __half* __restrict__ H, int N) {
    const int tid = threadIdx.x;
    const int lane = tid & 63;
    const int wv = tid >> 6;
    const int m = lane & 15;
    const int quad = lane >> 4;
    const int rb = blockIdx.x * 64;
    const int row = rb + wv * 16 + m;
    const int rowc = (row < N) ? row : (N - 1);

    // Prefetch X-frags for all 4 k-steps (k = s*32 + quad*8 + j).
    f16x8 xf[4];
    if constexpr (XFP32) {
        const float* X = (const float*)Xv;
#pragma unroll
        for (int s = 0; s < 4; s++) {
            const float4* p = (const float4*)(X + (size_t)rowc * 128 + s * 32 + quad * 8);
            float4 u0 = p[0], u1 = p[1];
            f16x8 f;
            f[0] = (_Float16)u0.x; f[1] = (_Float16)u0.y;
            f[2] = (_Float16)u0.z; f[3] = (_Float16)u0.w;
            f[4] = (_Float16)u1.x; f[5] = (_Float16)u1.y;
            f[6] = (_Float16)u1.z; f[7] = (_Float16)u1.w;
            xf[s] = f;
        }
    } else {
        const __half* X = (const __half*)Xv;
#pragma unroll
        for (int s = 0; s < 4; s++)
            xf[s] = *(const f16x8*)(X + (size_t)rowc * 128 + s * 32 + quad * 8);
    }

    constexpr int NT = BN / 16;
    f32x4 acc[NT];
#pragma unroll
    for (int t = 0; t < NT; t++) acc[t] = (f32x4){0.f, 0.f, 0.f, 0.f};

#pragma unroll
    for (int s = 0; s < 4; s++) {
#pragma unroll
        for (int t = 0; t < NT; t++) {
            f16x8 wf = *(const f16x8*)(Wt + (size_t)(t * 16 + m) * 128 + s * 32 + quad * 8);
            acc[t] = __builtin_amdgcn_mfma_f32_16x16x32_f16(wf, xf[s], acc[t], 0, 0, 0);
        }
    }

    if (row < N) {
        float sc = dinv[row];
#pragma unroll
        for (int t = 0; t < NT; t++) {
            __half2 h0 = __floats2half2_rn(sc * acc[t][0], sc * acc[t][1]);
            __half2 h1 = __floats2half2_rn(sc * acc[t][2], sc * acc[t][3]);
            __half2* dstp = (__half2*)(H + (size_t)row * BN + t * 16 + quad * 4);
            dstp[0] = h0;
            dstp[1] = h1;
        }
    }
}

// Aggregate: out[t] = dinv[t] * (sum_e w_e * Hs[src_e] + Hs[t]) + b
// Wave per node, 4 nodes per 256-thr block (R4 config -- measured best).
// DOUT==128: COLUMN-HALF dispatch (c0 = 0 or 32 in half2 units): all 64
// lanes hold meta slots; lanes 0-31 compute 32 half2 cols [c0, c0+32).
// H rows are 2x128B lines -> halves fetch disjoint lines (no byte overhead).
// DOUT==64: full-width fp32 out (unchanged).
template <int DOUT, bool RELU>
__global__ __launch_bounds__(256) void k_agg(const __half* __restrict__ H,
                                             const unsigned int* __restrict__ EW,
                                             const int* __restrict__ cnt,
                                             const float* __restrict__ dinv,
                                             const float* __restrict__ bias,
                                             void* __restrict__ Outv,
                                             int N, int cap, int c0) {
    int node = blockIdx.x * 4 + (threadIdx.x >> 6);
    if (node >= N) return;
    const int lane = threadIdx.x & 63;

    int c = cnt[node];  // wave-uniform
    c = (c < cap) ? c : cap;

    unsigned int meta = 0;
    if (lane < c) meta = EW[(size_t)node * cap + lane];

    float dt = dinv[node];

    if constexpr (DOUT == 128) {
        const bool act = lane < 32;
        const int col = c0 + (lane & 31);  // half2 column index
        const __half2* H2 = reinterpret_cast<const __half2*>(H);
        float a0 = 0.f, a1 = 0.f;
        if (act) {
            float2 hs = __half22float2(H2[(size_t)node * 64 + col]);
            a0 = hs.x; a1 = hs.y;  // self term, weight 1.0
        }
        int k = 0;
        for (; k + 8 <= c; k += 8) {
            __half2 hr[8]; float w[8];
#pragma unroll
            for (int u = 0; u < 8; u++) {
                unsigned int mm = RL(meta, k + u);
                w[u] = (float)(mm & WQ_MASK) * (1.0f / WQ_SCALE);
                if (act) hr[u] = H2[(size_t)(mm >> WQ_BITS) * 64 + col];
            }
            if (act) {
#pragma unroll
                for (int u = 0; u < 8; u++) {
                    float2 hv = __half22float2(hr[u]);
                    a0 = fmaf(w[u], hv.x, a0);
                    a1 = fmaf(w[u], hv.y, a1);
                }
            }
        }
        for (; k + 4 <= c; k += 4) {
            __half2 hr[4]; float w[4];
#pragma unroll
            for (int u = 0; u < 4; u++) {
                unsigned int mm = RL(meta, k + u);
                w[u] = (float)(mm & WQ_MASK) * (1.0f / WQ_SCALE);
                if (act) hr[u] = H2[(size_t)(mm >> WQ_BITS) * 64 + col];
            }
            if (act) {
#pragma unroll
                for (int u = 0; u < 4; u++) {
                    float2 hv = __half22float2(hr[u]);
                    a0 = fmaf(w[u], hv.x, a0);
                    a1 = fmaf(w[u], hv.y, a1);
                }
            }
        }
        for (; k < c; k++) {
            unsigned int mm = RL(meta, k);
            float w = (float)(mm & WQ_MASK) * (1.0f / WQ_SCALE);
            if (act) {
                float2 hv = __half22float2(H2[(size_t)(mm >> WQ_BITS) * 64 + col]);
                a0 = fmaf(w, hv.x, a0);
                a1 = fmaf(w, hv.y, a1);
            }
        }
        if (act) {
            float2 b = reinterpret_cast<const float2*>(bias)[col];
            a0 = fmaf(dt, a0, b.x);
            a1 = fmaf(dt, a1, b.y);
            if (RELU) { a0 = fmaxf(a0, 0.f); a1 = fmaxf(a1, 0.f); }
            reinterpret_cast<__half2*>(Outv)[(size_t)node * 64 + col] = __floats2half2_rn(a0, a1);
        }
    } else {  // DOUT == 64, fp32 out, full width
        float a = __half2float(H[(size_t)node * 64 + lane]);  // self term
        int k = 0;
        for (; k + 8 <= c; k += 8) {
            __half hr[8]; float w[8];
#pragma unroll
            for (int u = 0; u < 8; u++) {
                unsigned int mm = RL(meta, k + u);
                w[u] = (float)(mm & WQ_MASK) * (1.0f / WQ_SCALE);
                hr[u] = H[(size_t)(mm >> WQ_BITS) * 64 + lane];
            }
#pragma unroll
            for (int u = 0; u < 8; u++) a = fmaf(w[u], __half2float(hr[u]), a);
        }
        for (; k < c; k++) {
            unsigned int mm = RL(meta, k);
            float w = (float)(mm & WQ_MASK) * (1.0f / WQ_SCALE);
            a = fmaf(w, __half2float(H[(size_t)(mm >> WQ_BITS) * 64 + lane]), a);
        }
        a = fmaf(dt, a, bias[lane]);
        if (RELU) a = fmaxf(a, 0.f);
        ((float*)Outv)[(size_t)node * 64 + lane] = a;
    }
}

extern "C" void kernel_launch(void* const* d_in, const int* in_sizes, int n_in,
                              void* d_out, int out_size, void* d_ws, size_t ws_size,
                              hipStream_t stream) {
    const int N = in_sizes[0] / 128;   // x is [N,128]
    const int E = in_sizes[2];         // edge_weight is [E]

    const float* x  = (const float*)d_in[0];
    const int*   ei = (const int*)d_in[1];   // [2,E]: row0=src, row1=dst
    const int*   src = ei;
    const int*   dst = ei + E;
    const float* ew  = (const float*)d_in[2];
    const float* W0 = (const float*)d_in[3];
    const float* b0 = (const float*)d_in[4];
    const float* W1 = (const float*)d_in[5];
    const float* b1 = (const float*)d_in[6];
    const float* W2 = (const float*)d_in[7];
    const float* b2 = (const float*)d_in[8];

    // Partitioning: 64-node ranges; widen shift if N is huge so NP<=MAXNP.
    int shift = 6;
    while ((((N - 1) >> shift) + 1) > MAXNP) shift++;
    const int NP = ((N - 1) >> shift) + 1;

    // Workspace carve; bucket capacity adapts so we never write past d_ws.
    size_t fixed = (((size_t)N * 4 + 255) & ~(size_t)255)            // cnt
                 + (((size_t)N * 4 + 255) & ~(size_t)255)            // dinv
                 + 2 * (((size_t)N * 128 * 2 + 255) & ~(size_t)255)  // bufH, bufA fp16
                 + 3 * 33024                                         // wt0,wt1,wt2
                 + (((size_t)NP * 4 + 255) & ~(size_t)255)           // tail
                 + 2048;
    int cap = 64;
    if (ws_size > fixed) {
        size_t avail = (ws_size - fixed) / ((size_t)N * 4);
        if (avail < (size_t)cap) cap = (int)avail;
    } else {
        cap = 0;
    }

    char* p = (char*)d_ws;
    auto alloc = [&](size_t bytes) -> void* {
        void* r = (void*)p;
        p += (bytes + 255) & ~(size_t)255;
        return r;
    };
    int*          cnt  = (int*)alloc((size_t)N * 4);
    float*        dinv = (float*)alloc((size_t)N * 4);
    unsigned int* EW   = (unsigned int*)alloc((size_t)N * cap * 4);
    __half*       bufH = (__half*)alloc((size_t)N * 128 * 2);
    __half*       bufA = (__half*)alloc((size_t)N * 128 * 2);
    __half*       wt0  = (__half*)alloc(16384 * 2);
    __half*       wt1  = (__half*)alloc(16384 * 2);
    __half*       wt2  = (__half*)alloc(8192 * 2);
    int*          tail = (int*)alloc((size_t)NP * 4);

    // Phase-1 bin lists alias bufH (dead until gemm0): NP lists of ecap u64.
    u64* glist = (u64*)bufH;
    int  ecap  = (int)(((size_t)N * 128 * 2) / ((size_t)NP * 8));  // ~2047 here

    dim3 blk(256);
    int preN = (NP > 40960) ? NP : 40960;
    dim3 gPre((preN + 255) / 256);
    dim3 gBin(256);    // 1 block/CU; contiguous chunks, 2-pass (L2-hot)
    dim3 gFill(NP);    // 1 block per 64-node partition
    dim3 gGemm((N + 63) / 64);
    dim3 gWave((N + 3) / 4);

    k_pre<<<gPre, blk, 0, stream>>>(tail, NP, W0, W1, W2, wt0, wt1, wt2);
    k_bin<<<gBin, blk, 0, stream>>>(src, dst, ew, tail, glist, E, ecap, NP, shift);
    k_fill<<<gFill, blk, 0, stream>>>(tail, glist, ecap, cnt, dinv, EW, cap, N, shift);

    // layer 0 (x fp32 -> cvt in-kernel); agg split into column halves
    k_gemm<128, true><<<gGemm, blk, 0, stream>>>(x, wt0, dinv, bufH, N);
    k_agg<128, true><<<gWave, blk, 0, stream>>>(bufH, EW, cnt, dinv, b0, bufA, N, cap, 0);
    k_agg<128, true><<<gWave, blk, 0, stream>>>(bufH, EW, cnt, dinv, b0, bufA, N, cap, 32);

    // layer 1
    k_gemm<128, false><<<gGemm, blk, 0, stream>>>(bufA, wt1, dinv, bufH, N);
    k_agg<128, true><<<gWave, blk, 0, stream>>>(bufH, EW, cnt, dinv, b1, bufA, N, cap, 0);
    k_agg<128, true><<<gWave, blk, 0, stream>>>(bufH, EW, cnt, dinv, b1, bufA, N, cap, 32);

    // layer 2 (no relu, fp32 out, full width)
    k_gemm<64, false><<<gGemm, blk, 0, stream>>>(bufA, wt2, dinv, bufH, N);
    k_agg<64, false><<<gWave, blk, 0, stream>>>(bufH, EW, cnt, dinv, b2,
                                                d_out, N, cap, 0);
}

// Round 8
// 435.466 us; speedup vs baseline: 1.2689x; 1.2689x over previous
//
#include <hip/hip_runtime.h>
#include <hip/hip_fp16.h>

// GCN 3-layer encoder for MI355X.
// dinv folded into H (Hs = dinv*h, fp16); EW packs (src<<15 | w_q15) in 4 B.
// Build: two-phase, 64-node partitions (p=dst>>6) so slot counters live in
// LDS (R4: killed the 1.6M global-RMW bottleneck; 450->436 us).
// R8: agg is gather-INSTRUCTION-bound, not byte-bound (R6 column-split:
// half the bytes, same 64us). Fix: 16-deep gather batch per wave (R7 intent).
// R7 FAILED on a signedness bug: __builtin_amdgcn_readlane returns SIGNED
// int; inlining `RL(meta,..) >> 15` arithmetic-shifted negative values
// (src >= 65536 sets bit 31) -> sign-extended OOB gather -> NaN. R8 uses
// RLU() = (unsigned)readlane everywhere the packed word is shifted/masked.
// Only hr[16] lives across the wait (weights re-readlane'd at consume) so
// VGPR stays ~48 and occupancy holds. Everything else R4-exact.
// k_pre(init+wprep) -> k_bin -> k_fill -> [gemm_mfma -> aggregate] x3

typedef __attribute__((ext_vector_type(8))) _Float16 f16x8;
typedef __attribute__((ext_vector_type(4))) float f32x4;
typedef unsigned long long u64;

#define WQ_BITS 15
#define WQ_SCALE 32768.0f
#define WQ_MASK 32767u
#define MAXNP 2048

#define RLU(v, k) ((unsigned int)__builtin_amdgcn_readlane((v), (k)))

// Fused: zero tails + transpose W0/W1/W2 (fp32 [k][n]) into f16 Wt [n][k].
__global__ __launch_bounds__(256) void k_pre(int* tail, int NP,
                                             const float* __restrict__ W0,
                                             const float* __restrict__ W1,
                                             const float* __restrict__ W2,
                                             __half* __restrict__ wt0,
                                             __half* __restrict__ wt1,
                                             __half* __restrict__ wt2) {
    int id = blockIdx.x * 256 + threadIdx.x;
    if (id < NP) tail[id] = 0;
    if (id < 16384) {
        int n = id >> 7, k = id & 127;
        wt0[id] = __float2half(W0[k * 128 + n]);
    } else if (id < 32768) {
        int j = id - 16384, n = j >> 7, k = j & 127;
        wt1[j] = __float2half(W1[k * 128 + n]);
    } else if (id < 40960) {
        int j = id - 32768, n = j >> 7, k = j & 127;  // n in [0,64)
        wt2[j] = __float2half(W2[k * 64 + n]);
    }
}

// Phase 1: bin edges into NP per-node-range lists. Two passes over a
// contiguous per-block chunk (2nd pass L2-hot). Global atomics: one per
// (block, nonzero partition) -- ~390K over 1563 spread words.
__global__ __launch_bounds__(256) void k_bin(const int* __restrict__ src,
                                             const int* __restrict__ dst,
                                             const float* __restrict__ w,
                                             int* tail, u64* __restrict__ glist,
                                             int E, int ecap, int NP, int shift) {
    __shared__ unsigned int h[MAXNP];
    __shared__ int base[MAXNP];
    const int nb = gridDim.x;
    const int per = (E + nb - 1) / nb;
    const int e0 = blockIdx.x * per;
    const int e1 = (e0 + per < E) ? e0 + per : E;

    for (int i = threadIdx.x; i < NP; i += 256) h[i] = 0;
    __syncthreads();
    for (int e = e0 + (int)threadIdx.x; e < e1; e += 256) {
        int p = dst[e] >> shift;
        atomicAdd(&h[p], 1u);
    }
    __syncthreads();
    for (int i = threadIdx.x; i < NP; i += 256) {
        unsigned int c = h[i];
        base[i] = c ? atomicAdd(&tail[i], (int)c) : 0;
    }
    __syncthreads();
    for (int e = e0 + (int)threadIdx.x; e < e1; e += 256) {
        int t = dst[e];  // L2-hot (pass 1 cached it)
        int p = t >> shift;
        int s = __builtin_nontemporal_load(src + e);
        float we = __builtin_nontemporal_load(w + e);
        int wq = (int)(we * WQ_SCALE + 0.5f);
        wq = (wq < (int)WQ_MASK) ? wq : (int)WQ_MASK;
        u64 v = ((u64)(unsigned)t << 32) |
                ((unsigned)s << WQ_BITS) | (unsigned)wq;
        unsigned int idx = atomicSub(&h[p], 1u) - 1u;  // LDS, order-free
        int pos = base[p] + (int)idx;
        if (pos < ecap) glist[(size_t)p * ecap + pos] = v;
    }
}

// Phase 2: one block per partition (64-node range). Slot assignment via LDS
// atomics; EW plain stores into the partition's own L2-resident region.
// Also emits cnt (plain store) and dinv (LDS float accumulation of wq).
__global__ __launch_bounds__(256) void k_fill(const int* __restrict__ tail,
                                              const u64* __restrict__ glist,
                                              int ecap, int* __restrict__ cnt,
                                              float* __restrict__ dinv,
                                              unsigned int* __restrict__ EW,
                                              int cap, int N, int shift) {
    __shared__ unsigned int lcnt[MAXNP];
    __shared__ float lws[MAXNP];
    const int p = blockIdx.x;
    const int np = 1 << shift;
    const int t0 = p << shift;
    for (int i = threadIdx.x; i < np; i += 256) { lcnt[i] = 0; lws[i] = 0.f; }
    __syncthreads();
    int n = tail[p];
    if (n > ecap) n = ecap;
    const u64* L = glist + (size_t)p * ecap;
    for (int j = threadIdx.x; j < n; j += 256) {
        u64 v = L[j];
        int t = (int)(v >> 32);
        int loc = t - t0;
        unsigned int k = atomicAdd(&lcnt[loc], 1u);  // LDS
        if ((int)k < cap) {
            EW[(size_t)t * cap + k] = (unsigned int)v;
            atomicAdd(&lws[loc], (float)((unsigned int)v & WQ_MASK));  // LDS f32
        }
    }
    __syncthreads();
    for (int i = threadIdx.x; i < np; i += 256) {
        int t = t0 + i;
        if (t < N) {
            int c = (int)lcnt[i];
            c = (c < cap) ? c : cap;
            cnt[t] = c;
            dinv[t] = 1.0f / sqrtf(1.0f + lws[i] * (1.0f / WQ_SCALE));
        }
    }
}

// MFMA GEMM: H[N x BN] = dinv[r]*(X[N x 128] @ W[128 x BN]) as fp16.
// Per wave: 16 rows x BN cols. Operand swap: A:=W^T-frag (from Wt[n][k]),
// B:=X^T-frag -> each lane holds 4 consecutive H-cols -> 8 B stores. No LDS.
// dinv read from global (computed by k_fill).
template <int BN, bool XFP32>
__global__ __launch_bounds__(256, 4) void k_gemm(const void* __restrict__ Xv,
                                                 const __half* __restrict__ Wt,
                                                 const float* __restrict__ dinv,
                                                 __half* __restrict__ H, int N) {
    const int tid = threadIdx.x;
    const int lane = tid & 63;
    const int wv = tid >> 6;
    const int m = lane & 15;
    const int quad = lane >> 4;
    const int rb = blockIdx.x * 64;
    const int row = rb + wv * 16 + m;
    const int rowc = (row < N) ? row : (N - 1);

    // Prefetch X-frags for all 4 k-steps (k = s*32 + quad*8 + j).
    f16x8 xf[4];
    if constexpr (XFP32) {
        const float* X = (const float*)Xv;
#pragma unroll
        for (int s = 0; s < 4; s++) {
            const float4* p = (const float4*)(X + (size_t)rowc * 128 + s * 32 + quad * 8);
            float4 u0 = p[0], u1 = p[1];
            f16x8 f;
            f[0] = (_Float16)u0.x; f[1] = (_Float16)u0.y;
            f[2] = (_Float16)u0.z; f[3] = (_Float16)u0.w;
            f[4] = (_Float16)u1.x; f[5] = (_Float16)u1.y;
            f[6] = (_Float16)u1.z; f[7] = (_Float16)u1.w;
            xf[s] = f;
        }
    } else {
        const __half* X = (const __half*)Xv;
#pragma unroll
        for (int s = 0; s < 4; s++)
            xf[s] = *(const f16x8*)(X + (size_t)rowc * 128 + s * 32 + quad * 8);
    }

    constexpr int NT = BN / 16;
    f32x4 acc[NT];
#pragma unroll
    for (int t = 0; t < NT; t++) acc[t] = (f32x4){0.f, 0.f, 0.f, 0.f};

#pragma unroll
    for (int s = 0; s < 4; s++) {
#pragma unroll
        for (int t = 0; t < NT; t++) {
            f16x8 wf = *(const f16x8*)(Wt + (size_t)(t * 16 + m) * 128 + s * 32 + quad * 8);
            acc[t] = __builtin_amdgcn_mfma_f32_16x16x32_f16(wf, xf[s], acc[t], 0, 0, 0);
        }
    }

    if (row < N) {
        float sc = dinv[row];
#pragma unroll
        for (int t = 0; t < NT; t++) {
            __half2 h0 = __floats2half2_rn(sc * acc[t][0], sc * acc[t][1]);
            __half2 h1 = __floats2half2_rn(sc * acc[t][2], sc * acc[t][3]);
            __half2* dstp = (__half2*)(H + (size_t)row * BN + t * 16 + quad * 4);
            dstp[0] = h0;
            dstp[1] = h1;
        }
    }
}

// Aggregate: out[t] = dinv[t] * (sum_e w_e * Hs[src_e] + Hs[t]) + b
// Wave per node, 4 nodes per 256-thr block (measured-best). 16-deep gather
// pipeline: issue 16 row loads, then consume (weights re-readlane'd at
// consume so only hr[16] lives across the wait -> VGPR ~48, occupancy
// holds). All packed-word shifts via RLU (unsigned) -- R7's NaN was a
// signed readlane arithmetic-shift. Tiers 16/8/4/1.
template <int DOUT, bool RELU>
__global__ __launch_bounds__(256) void k_agg(const __half* __restrict__ H,
                                             const unsigned int* __restrict__ EW,
                                             const int* __restrict__ cnt,
                                             const float* __restrict__ dinv,
                                             const float* __restrict__ bias,
                                             void* __restrict__ Outv,
                                             int N, int cap) {
    int node = blockIdx.x * 4 + (threadIdx.x >> 6);
    if (node >= N) return;
    const int lane = threadIdx.x & 63;

    int c = cnt[node];  // wave-uniform
    c = (c < cap) ? c : cap;

    unsigned int meta = 0;
    if (lane < c) meta = EW[(size_t)node * cap + lane];

    float dt = dinv[node];

    if constexpr (DOUT == 128) {
        const __half2* H2 = reinterpret_cast<const __half2*>(H);
        float2 hs = __half22float2(H2[(size_t)node * 64 + lane]);
        float a0 = hs.x, a1 = hs.y;  // self term, weight 1.0
        int k = 0;
        for (; k + 16 <= c; k += 16) {
            __half2 hr[16];
#pragma unroll
            for (int u = 0; u < 16; u++)
                hr[u] = H2[(size_t)(RLU(meta, k + u) >> WQ_BITS) * 64 + lane];
#pragma unroll
            for (int u = 0; u < 16; u++) {
                float w = (float)(RLU(meta, k + u) & WQ_MASK) * (1.0f / WQ_SCALE);
                float2 hv = __half22float2(hr[u]);
                a0 = fmaf(w, hv.x, a0);
                a1 = fmaf(w, hv.y, a1);
            }
        }
        for (; k + 8 <= c; k += 8) {
            __half2 hr[8];
#pragma unroll
            for (int u = 0; u < 8; u++)
                hr[u] = H2[(size_t)(RLU(meta, k + u) >> WQ_BITS) * 64 + lane];
#pragma unroll
            for (int u = 0; u < 8; u++) {
                float w = (float)(RLU(meta, k + u) & WQ_MASK) * (1.0f / WQ_SCALE);
                float2 hv = __half22float2(hr[u]);
                a0 = fmaf(w, hv.x, a0);
                a1 = fmaf(w, hv.y, a1);
            }
        }
        for (; k + 4 <= c; k += 4) {
            __half2 hr[4];
#pragma unroll
            for (int u = 0; u < 4; u++)
                hr[u] = H2[(size_t)(RLU(meta, k + u) >> WQ_BITS) * 64 + lane];
#pragma unroll
            for (int u = 0; u < 4; u++) {
                float w = (float)(RLU(meta, k + u) & WQ_MASK) * (1.0f / WQ_SCALE);
                float2 hv = __half22float2(hr[u]);
                a0 = fmaf(w, hv.x, a0);
                a1 = fmaf(w, hv.y, a1);
            }
        }
        for (; k < c; k++) {
            unsigned int mm = RLU(meta, k);
            float w = (float)(mm & WQ_MASK) * (1.0f / WQ_SCALE);
            float2 hv = __half22float2(H2[(size_t)(mm >> WQ_BITS) * 64 + lane]);
            a0 = fmaf(w, hv.x, a0);
            a1 = fmaf(w, hv.y, a1);
        }
        float2 b = reinterpret_cast<const float2*>(bias)[lane];
        a0 = fmaf(dt, a0, b.x);
        a1 = fmaf(dt, a1, b.y);
        if (RELU) { a0 = fmaxf(a0, 0.f); a1 = fmaxf(a1, 0.f); }
        reinterpret_cast<__half2*>(Outv)[(size_t)node * 64 + lane] = __floats2half2_rn(a0, a1);
    } else {  // DOUT == 64, fp32 out
        float a = __half2float(H[(size_t)node * 64 + lane]);  // self term
        int k = 0;
        for (; k + 16 <= c; k += 16) {
            __half hr[16];
#pragma unroll
            for (int u = 0; u < 16; u++)
                hr[u] = H[(size_t)(RLU(meta, k + u) >> WQ_BITS) * 64 + lane];
#pragma unroll
            for (int u = 0; u < 16; u++) {
                float w = (float)(RLU(meta, k + u) & WQ_MASK) * (1.0f / WQ_SCALE);
                a = fmaf(w, __half2float(hr[u]), a);
            }
        }
        for (; k + 8 <= c; k += 8) {
            __half hr[8];
#pragma unroll
            for (int u = 0; u < 8; u++)
                hr[u] = H[(size_t)(RLU(meta, k + u) >> WQ_BITS) * 64 + lane];
#pragma unroll
            for (int u = 0; u < 8; u++) {
                float w = (float)(RLU(meta, k + u) & WQ_MASK) * (1.0f / WQ_SCALE);
                a = fmaf(w, __half2float(hr[u]), a);
            }
        }
        for (; k < c; k++) {
            unsigned int mm = RLU(meta, k);
            float w = (float)(mm & WQ_MASK) * (1.0f / WQ_SCALE);
            a = fmaf(w, __half2float(H[(size_t)(mm >> WQ_BITS) * 64 + lane]), a);
        }
        a = fmaf(dt, a, bias[lane]);
        if (RELU) a = fmaxf(a, 0.f);
        ((float*)Outv)[(size_t)node * 64 + lane] = a;
    }
}

extern "C" void kernel_launch(void* const* d_in, const int* in_sizes, int n_in,
                              void* d_out, int out_size, void* d_ws, size_t ws_size,
                              hipStream_t stream) {
    const int N = in_sizes[0] / 128;   // x is [N,128]
    const int E = in_sizes[2];         // edge_weight is [E]

    const float* x  = (const float*)d_in[0];
    const int*   ei = (const int*)d_in[1];   // [2,E]: row0=src, row1=dst
    const int*   src = ei;
    const int*   dst = ei + E;
    const float* ew  = (const float*)d_in[2];
    const float* W0 = (const float*)d_in[3];
    const float* b0 = (const float*)d_in[4];
    const float* W1 = (const float*)d_in[5];
    const float* b1 = (const float*)d_in[6];
    const float* W2 = (const float*)d_in[7];
    const float* b2 = (const float*)d_in[8];

    // Partitioning: 64-node ranges; widen shift if N is huge so NP<=MAXNP.
    int shift = 6;
    while ((((N - 1) >> shift) + 1) > MAXNP) shift++;
    const int NP = ((N - 1) >> shift) + 1;

    // Workspace carve; bucket capacity adapts so we never write past d_ws.
    size_t fixed = (((size_t)N * 4 + 255) & ~(size_t)255)            // cnt
                 + (((size_t)N * 4 + 255) & ~(size_t)255)            // dinv
                 + 2 * (((size_t)N * 128 * 2 + 255) & ~(size_t)255)  // bufH, bufA fp16
                 + 3 * 33024                                         // wt0,wt1,wt2
                 + (((size_t)NP * 4 + 255) & ~(size_t)255)           // tail
                 + 2048;
    int cap = 64;
    if (ws_size > fixed) {
        size_t avail = (ws_size - fixed) / ((size_t)N * 4);
        if (avail < (size_t)cap) cap = (int)avail;
    } else {
        cap = 0;
    }

    char* p = (char*)d_ws;
    auto alloc = [&](size_t bytes) -> void* {
        void* r = (void*)p;
        p += (bytes + 255) & ~(size_t)255;
        return r;
    };
    int*          cnt  = (int*)alloc((size_t)N * 4);
    float*        dinv = (float*)alloc((size_t)N * 4);
    unsigned int* EW   = (unsigned int*)alloc((size_t)N * cap * 4);
    __half*       bufH = (__half*)alloc((size_t)N * 128 * 2);
    __half*       bufA = (__half*)alloc((size_t)N * 128 * 2);
    __half*       wt0  = (__half*)alloc(16384 * 2);
    __half*       wt1  = (__half*)alloc(16384 * 2);
    __half*       wt2  = (__half*)alloc(8192 * 2);
    int*          tail = (int*)alloc((size_t)NP * 4);

    // Phase-1 bin lists alias bufH (dead until gemm0): NP lists of ecap u64.
    u64* glist = (u64*)bufH;
    int  ecap  = (int)(((size_t)N * 128 * 2) / ((size_t)NP * 8));  // ~2047 here

    dim3 blk(256);
    int preN = (NP > 40960) ? NP : 40960;
    dim3 gPre((preN + 255) / 256);
    dim3 gBin(256);    // 1 block/CU; contiguous chunks, 2-pass (L2-hot)
    dim3 gFill(NP);    // 1 block per 64-node partition
    dim3 gGemm((N + 63) / 64);
    dim3 gWave((N + 3) / 4);

    k_pre<<<gPre, blk, 0, stream>>>(tail, NP, W0, W1, W2, wt0, wt1, wt2);
    k_bin<<<gBin, blk, 0, stream>>>(src, dst, ew, tail, glist, E, ecap, NP, shift);
    k_fill<<<gFill, blk, 0, stream>>>(tail, glist, ecap, cnt, dinv, EW, cap, N, shift);

    // layer 0 (x fp32 -> cvt in-kernel)
    k_gemm<128, true><<<gGemm, blk, 0, stream>>>(x, wt0, dinv, bufH, N);
    k_agg<128, true><<<gWave, blk, 0, stream>>>(bufH, EW, cnt, dinv, b0, bufA, N, cap);

    // layer 1
    k_gemm<128, false><<<gGemm, blk, 0, stream>>>(bufA, wt1, dinv, bufH, N);
    k_agg<128, true><<<gWave, blk, 0, stream>>>(bufH, EW, cnt, dinv, b1, bufA, N, cap);

    // layer 2 (no relu, fp32 out)
    k_gemm<64, false><<<gGemm, blk, 0, stream>>>(bufA, wt2, dinv, bufH, N);
    k_agg<64, false><<<gWave, blk, 0, stream>>>(bufH, EW, cnt, dinv, b2,
                                                d_out, N, cap);
}

// Round 9
// 427.257 us; speedup vs baseline: 1.2933x; 1.0192x over previous
//
#include <hip/hip_runtime.h>
#include <hip/hip_fp16.h>

// GCN 3-layer encoder for MI355X.
// dinv folded into H (Hs = dinv*h, fp16); EW packs (src<<15 | w_q15) in 4 B.
// Build: two-phase, 64-node partitions (p=dst>>6), slot counters in LDS (R4).
// R9: agg gather cost is PER-INSTRUCTION (~23 cyc/CU), independent of bytes
// (R6: half bytes, same time), lines (R6), and per-wave depth (R8: 16-deep
// null). So: pack 4 edges per gather instruction via 16B/lane dwordx4 --
// 16 lanes cover one 256B row, q=lane>>4 selects edge in group; per-lane
// fp32 accum of 8 cols; shfl_xor(16,32) reduce; q==0 lanes store the row.
// DOUT=64 (128B rows): 8 lanes/row -> 8 edges/instr, reduce xor 8/16/32.
// All packed-word shifts on (unsigned) -- readlane/shfl return SIGNED (R7).
// k_pre(init+wprep) -> k_bin -> k_fill -> [gemm_mfma -> aggregate] x3

typedef __attribute__((ext_vector_type(8))) _Float16 f16x8;
typedef __attribute__((ext_vector_type(4))) float f32x4;
typedef unsigned long long u64;

#define WQ_BITS 15
#define WQ_SCALE 32768.0f
#define WQ_MASK 32767u
#define MAXNP 2048

#define SHFLU(v, k) ((unsigned int)__shfl((int)(v), (k), 64))

// Fused: zero tails + transpose W0/W1/W2 (fp32 [k][n]) into f16 Wt [n][k].
__global__ __launch_bounds__(256) void k_pre(int* tail, int NP,
                                             const float* __restrict__ W0,
                                             const float* __restrict__ W1,
                                             const float* __restrict__ W2,
                                             __half* __restrict__ wt0,
                                             __half* __restrict__ wt1,
                                             __half* __restrict__ wt2) {
    int id = blockIdx.x * 256 + threadIdx.x;
    if (id < NP) tail[id] = 0;
    if (id < 16384) {
        int n = id >> 7, k = id & 127;
        wt0[id] = __float2half(W0[k * 128 + n]);
    } else if (id < 32768) {
        int j = id - 16384, n = j >> 7, k = j & 127;
        wt1[j] = __float2half(W1[k * 128 + n]);
    } else if (id < 40960) {
        int j = id - 32768, n = j >> 7, k = j & 127;  // n in [0,64)
        wt2[j] = __float2half(W2[k * 64 + n]);
    }
}

// Phase 1: bin edges into NP per-node-range lists. Two passes over a
// contiguous per-block chunk (2nd pass L2-hot). Global atomics: one per
// (block, nonzero partition) -- ~390K over 1563 spread words.
__global__ __launch_bounds__(256) void k_bin(const int* __restrict__ src,
                                             const int* __restrict__ dst,
                                             const float* __restrict__ w,
                                             int* tail, u64* __restrict__ glist,
                                             int E, int ecap, int NP, int shift) {
    __shared__ unsigned int h[MAXNP];
    __shared__ int base[MAXNP];
    const int nb = gridDim.x;
    const int per = (E + nb - 1) / nb;
    const int e0 = blockIdx.x * per;
    const int e1 = (e0 + per < E) ? e0 + per : E;

    for (int i = threadIdx.x; i < NP; i += 256) h[i] = 0;
    __syncthreads();
    for (int e = e0 + (int)threadIdx.x; e < e1; e += 256) {
        int p = dst[e] >> shift;
        atomicAdd(&h[p], 1u);
    }
    __syncthreads();
    for (int i = threadIdx.x; i < NP; i += 256) {
        unsigned int c = h[i];
        base[i] = c ? atomicAdd(&tail[i], (int)c) : 0;
    }
    __syncthreads();
    for (int e = e0 + (int)threadIdx.x; e < e1; e += 256) {
        int t = dst[e];  // L2-hot (pass 1 cached it)
        int p = t >> shift;
        int s = __builtin_nontemporal_load(src + e);
        float we = __builtin_nontemporal_load(w + e);
        int wq = (int)(we * WQ_SCALE + 0.5f);
        wq = (wq < (int)WQ_MASK) ? wq : (int)WQ_MASK;
        u64 v = ((u64)(unsigned)t << 32) |
                ((unsigned)s << WQ_BITS) | (unsigned)wq;
        unsigned int idx = atomicSub(&h[p], 1u) - 1u;  // LDS, order-free
        int pos = base[p] + (int)idx;
        if (pos < ecap) glist[(size_t)p * ecap + pos] = v;
    }
}

// Phase 2: one block per partition (64-node range). Slot assignment via LDS
// atomics; EW plain stores into the partition's own L2-resident region.
// Also emits cnt (plain store) and dinv (LDS float accumulation of wq).
__global__ __launch_bounds__(256) void k_fill(const int* __restrict__ tail,
                                              const u64* __restrict__ glist,
                                              int ecap, int* __restrict__ cnt,
                                              float* __restrict__ dinv,
                                              unsigned int* __restrict__ EW,
                                              int cap, int N, int shift) {
    __shared__ unsigned int lcnt[MAXNP];
    __shared__ float lws[MAXNP];
    const int p = blockIdx.x;
    const int np = 1 << shift;
    const int t0 = p << shift;
    for (int i = threadIdx.x; i < np; i += 256) { lcnt[i] = 0; lws[i] = 0.f; }
    __syncthreads();
    int n = tail[p];
    if (n > ecap) n = ecap;
    const u64* L = glist + (size_t)p * ecap;
    for (int j = threadIdx.x; j < n; j += 256) {
        u64 v = L[j];
        int t = (int)(v >> 32);
        int loc = t - t0;
        unsigned int k = atomicAdd(&lcnt[loc], 1u);  // LDS
        if ((int)k < cap) {
            EW[(size_t)t * cap + k] = (unsigned int)v;
            atomicAdd(&lws[loc], (float)((unsigned int)v & WQ_MASK));  // LDS f32
        }
    }
    __syncthreads();
    for (int i = threadIdx.x; i < np; i += 256) {
        int t = t0 + i;
        if (t < N) {
            int c = (int)lcnt[i];
            c = (c < cap) ? c : cap;
            cnt[t] = c;
            dinv[t] = 1.0f / sqrtf(1.0f + lws[i] * (1.0f / WQ_SCALE));
        }
    }
}

// MFMA GEMM: H[N x BN] = dinv[r]*(X[N x 128] @ W[128 x BN]) as fp16.
// Per wave: 16 rows x BN cols. Operand swap: A:=W^T-frag (from Wt[n][k]),
// B:=X^T-frag -> each lane holds 4 consecutive H-cols -> 8 B stores. No LDS.
// dinv read from global (computed by k_fill).
template <int BN, bool XFP32>
__global__ __launch_bounds__(256, 4) void k_gemm(const void* __restrict__ Xv,
                                                 const __half* __restrict__ Wt,
                                                 const float* __restrict__ dinv,
                                                 __half* __restrict__ H, int N) {
    const int tid = threadIdx.x;
    const int lane = tid & 63;
    const int wv = tid >> 6;
    const int m = lane & 15;
    const int quad = lane >> 4;
    const int rb = blockIdx.x * 64;
    const int row = rb + wv * 16 + m;
    const int rowc = (row < N) ? row : (N - 1);

    // Prefetch X-frags for all 4 k-steps (k = s*32 + quad*8 + j).
    f16x8 xf[4];
    if constexpr (XFP32) {
        const float* X = (const float*)Xv;
#pragma unroll
        for (int s = 0; s < 4; s++) {
            const float4* p = (const float4*)(X + (size_t)rowc * 128 + s * 32 + quad * 8);
            float4 u0 = p[0], u1 = p[1];
            f16x8 f;
            f[0] = (_Float16)u0.x; f[1] = (_Float16)u0.y;
            f[2] = (_Float16)u0.z; f[3] = (_Float16)u0.w;
            f[4] = (_Float16)u1.x; f[5] = (_Float16)u1.y;
            f[6] = (_Float16)u1.z; f[7] = (_Float16)u1.w;
            xf[s] = f;
        }
    } else {
        const __half* X = (const __half*)Xv;
#pragma unroll
        for (int s = 0; s < 4; s++)
            xf[s] = *(const f16x8*)(X + (size_t)rowc * 128 + s * 32 + quad * 8);
    }

    constexpr int NT = BN / 16;
    f32x4 acc[NT];
#pragma unroll
    for (int t = 0; t < NT; t++) acc[t] = (f32x4){0.f, 0.f, 0.f, 0.f};

#pragma unroll
    for (int s = 0; s < 4; s++) {
#pragma unroll
        for (int t = 0; t < NT; t++) {
            f16x8 wf = *(const f16x8*)(Wt + (size_t)(t * 16 + m) * 128 + s * 32 + quad * 8);
            acc[t] = __builtin_amdgcn_mfma_f32_16x16x32_f16(wf, xf[s], acc[t], 0, 0, 0);
        }
    }

    if (row < N) {
        float sc = dinv[row];
#pragma unroll
        for (int t = 0; t < NT; t++) {
            __half2 h0 = __floats2half2_rn(sc * acc[t][0], sc * acc[t][1]);
            __half2 h1 = __floats2half2_rn(sc * acc[t][2], sc * acc[t][3]);
            __half2* dstp = (__half2*)(H + (size_t)row * BN + t * 16 + quad * 4);
            dstp[0] = h0;
            dstp[1] = h1;
        }
    }
}

// Aggregate: out[t] = dinv[t] * (sum_e w_e * Hs[src_e] + Hs[t]) + b
// Wave per node, 4 nodes per 256-thr block. PACKED GATHER: 16B/lane dwordx4;
// DOUT=128: 16 lanes cover a 256B row -> 4 edges per load instruction
// (q=lane>>4 selects edge in group, part=lane&15 selects 16B chunk).
// Per-lane fp32 accum of 8 cols; shfl_xor(16,32) reduce; q==0 lanes add
// self+bias, store 16B. DOUT=64: 128B rows -> 8 edges/instr (q=lane>>3,
// part=lane&7), reduce xor 8/16/32, fp32 out.
template <int DOUT, bool RELU>
__global__ __launch_bounds__(256) void k_agg(const __half* __restrict__ H,
                                             const unsigned int* __restrict__ EW,
                                             const int* __restrict__ cnt,
                                             const float* __restrict__ dinv,
                                             const float* __restrict__ bias,
                                             void* __restrict__ Outv,
                                             int N, int cap) {
    int node = blockIdx.x * 4 + (threadIdx.x >> 6);
    if (node >= N) return;
    const int lane = threadIdx.x & 63;

    int c = cnt[node];  // wave-uniform
    c = (c < cap) ? c : cap;

    unsigned int meta = 0;
    if (lane < c) meta = EW[(size_t)node * cap + lane];

    float dt = dinv[node];

    if constexpr (DOUT == 128) {
        const int part = lane & 15;  // 16B chunk of the 256B row
        const int q = lane >> 4;     // edge within group of 4
        float acc[8];
#pragma unroll
        for (int j = 0; j < 8; j++) acc[j] = 0.f;

        int k = 0;
        // 16 edges per superstep: 4 packed gathers in flight
        for (; k + 16 <= c; k += 16) {
            f16x8 hv[4];
            float w[4];
#pragma unroll
            for (int g = 0; g < 4; g++) {
                unsigned int mm = SHFLU(meta, k + g * 4 + q);
                w[g] = (float)(mm & WQ_MASK) * (1.0f / WQ_SCALE);
                hv[g] = *(const f16x8*)(H + (size_t)(mm >> WQ_BITS) * 128 + part * 8);
            }
#pragma unroll
            for (int g = 0; g < 4; g++)
#pragma unroll
                for (int j = 0; j < 8; j++)
                    acc[j] = fmaf(w[g], (float)hv[g][j], acc[j]);
        }
        // masked 4-edge groups for the tail
        for (; k < c; k += 4) {
            int idx = k + q;
            unsigned int mm = SHFLU(meta, (idx < c) ? idx : 0);
            float w = (idx < c) ? (float)(mm & WQ_MASK) * (1.0f / WQ_SCALE) : 0.f;
            unsigned int row = (idx < c) ? (mm >> WQ_BITS) : (unsigned int)node;
            f16x8 hv = *(const f16x8*)(H + (size_t)row * 128 + part * 8);
#pragma unroll
            for (int j = 0; j < 8; j++)
                acc[j] = fmaf(w, (float)hv[j], acc[j]);
        }
        // reduce edge quadrants: lanes {part, part+16, part+32, part+48}
#pragma unroll
        for (int j = 0; j < 8; j++) {
            acc[j] += __shfl_xor(acc[j], 16, 64);
            acc[j] += __shfl_xor(acc[j], 32, 64);
        }
        if (q == 0) {
            f16x8 sv = *(const f16x8*)(H + (size_t)node * 128 + part * 8);
            f32x4 b0v = *(const f32x4*)(bias + part * 8);
            f32x4 b1v = *(const f32x4*)(bias + part * 8 + 4);
            f16x8 ov;
#pragma unroll
            for (int j = 0; j < 8; j++) {
                float bj = (j < 4) ? b0v[j] : b1v[j - 4];
                float v = fmaf(dt, acc[j] + (float)sv[j], bj);
                if (RELU) v = fmaxf(v, 0.f);
                ov[j] = (_Float16)v;
            }
            *(f16x8*)((__half*)Outv + (size_t)node * 128 + part * 8) = ov;
        }
    } else {  // DOUT == 64, fp32 out; 128B rows -> 8 edges per instruction
        const int part = lane & 7;  // 16B chunk of the 128B row
        const int q = lane >> 3;    // edge within group of 8
        float acc[8];
#pragma unroll
        for (int j = 0; j < 8; j++) acc[j] = 0.f;

        int k = 0;
        // 32 edges per superstep: 4 packed gathers in flight
        for (; k + 32 <= c; k += 32) {
            f16x8 hv[4];
            float w[4];
#pragma unroll
            for (int g = 0; g < 4; g++) {
                unsigned int mm = SHFLU(meta, k + g * 8 + q);
                w[g] = (float)(mm & WQ_MASK) * (1.0f / WQ_SCALE);
                hv[g] = *(const f16x8*)(H + (size_t)(mm >> WQ_BITS) * 64 + part * 8);
            }
#pragma unroll
            for (int g = 0; g < 4; g++)
#pragma unroll
                for (int j = 0; j < 8; j++)
                    acc[j] = fmaf(w[g], (float)hv[g][j], acc[j]);
        }
        // masked 8-edge groups for the tail
        for (; k < c; k += 8) {
            int idx = k + q;
            unsigned int mm = SHFLU(meta, (idx < c) ? idx : 0);
            float w = (idx < c) ? (float)(mm & WQ_MASK) * (1.0f / WQ_SCALE) : 0.f;
            unsigned int row = (idx < c) ? (mm >> WQ_BITS) : (unsigned int)node;
            f16x8 hv = *(const f16x8*)(H + (size_t)row * 64 + part * 8);
#pragma unroll
            for (int j = 0; j < 8; j++)
                acc[j] = fmaf(w, (float)hv[j], acc[j]);
        }
        // reduce edge octants: xor 8, 16, 32
#pragma unroll
        for (int j = 0; j < 8; j++) {
            acc[j] += __shfl_xor(acc[j], 8, 64);
            acc[j] += __shfl_xor(acc[j], 16, 64);
            acc[j] += __shfl_xor(acc[j], 32, 64);
        }
        if (q == 0) {
            f16x8 sv = *(const f16x8*)(H + (size_t)node * 64 + part * 8);
            f32x4 b0v = *(const f32x4*)(bias + part * 8);
            f32x4 b1v = *(const f32x4*)(bias + part * 8 + 4);
            f32x4 o0, o1;
#pragma unroll
            for (int j = 0; j < 8; j++) {
                float bj = (j < 4) ? b0v[j] : b1v[j - 4];
                float v = fmaf(dt, acc[j] + (float)sv[j], bj);
                if (RELU) v = fmaxf(v, 0.f);
                if (j < 4) o0[j] = v; else o1[j - 4] = v;
            }
            float* op = (float*)Outv + (size_t)node * 64 + part * 8;
            *(f32x4*)op = o0;
            *(f32x4*)(op + 4) = o1;
        }
    }
}

extern "C" void kernel_launch(void* const* d_in, const int* in_sizes, int n_in,
                              void* d_out, int out_size, void* d_ws, size_t ws_size,
                              hipStream_t stream) {
    const int N = in_sizes[0] / 128;   // x is [N,128]
    const int E = in_sizes[2];         // edge_weight is [E]

    const float* x  = (const float*)d_in[0];
    const int*   ei = (const int*)d_in[1];   // [2,E]: row0=src, row1=dst
    const int*   src = ei;
    const int*   dst = ei + E;
    const float* ew  = (const float*)d_in[2];
    const float* W0 = (const float*)d_in[3];
    const float* b0 = (const float*)d_in[4];
    const float* W1 = (const float*)d_in[5];
    const float* b1 = (const float*)d_in[6];
    const float* W2 = (const float*)d_in[7];
    const float* b2 = (const float*)d_in[8];

    // Partitioning: 64-node ranges; widen shift if N is huge so NP<=MAXNP.
    int shift = 6;
    while ((((N - 1) >> shift) + 1) > MAXNP) shift++;
    const int NP = ((N - 1) >> shift) + 1;

    // Workspace carve; bucket capacity adapts so we never write past d_ws.
    size_t fixed = (((size_t)N * 4 + 255) & ~(size_t)255)            // cnt
                 + (((size_t)N * 4 + 255) & ~(size_t)255)            // dinv
                 + 2 * (((size_t)N * 128 * 2 + 255) & ~(size_t)255)  // bufH, bufA fp16
                 + 3 * 33024                                         // wt0,wt1,wt2
                 + (((size_t)NP * 4 + 255) & ~(size_t)255)           // tail
                 + 2048;
    int cap = 64;
    if (ws_size > fixed) {
        size_t avail = (ws_size - fixed) / ((size_t)N * 4);
        if (avail < (size_t)cap) cap = (int)avail;
    } else {
        cap = 0;
    }

    char* p = (char*)d_ws;
    auto alloc = [&](size_t bytes) -> void* {
        void* r = (void*)p;
        p += (bytes + 255) & ~(size_t)255;
        return r;
    };
    int*          cnt  = (int*)alloc((size_t)N * 4);
    float*        dinv = (float*)alloc((size_t)N * 4);
    unsigned int* EW   = (unsigned int*)alloc((size_t)N * cap * 4);
    __half*       bufH = (__half*)alloc((size_t)N * 128 * 2);
    __half*       bufA = (__half*)alloc((size_t)N * 128 * 2);
    __half*       wt0  = (__half*)alloc(16384 * 2);
    __half*       wt1  = (__half*)alloc(16384 * 2);
    __half*       wt2  = (__half*)alloc(8192 * 2);
    int*          tail = (int*)alloc((size_t)NP * 4);

    // Phase-1 bin lists alias bufH (dead until gemm0): NP lists of ecap u64.
    u64* glist = (u64*)bufH;
    int  ecap  = (int)(((size_t)N * 128 * 2) / ((size_t)NP * 8));  // ~2047 here

    dim3 blk(256);
    int preN = (NP > 40960) ? NP : 40960;
    dim3 gPre((preN + 255) / 256);
    dim3 gBin(256);    // 1 block/CU; contiguous chunks, 2-pass (L2-hot)
    dim3 gFill(NP);    // 1 block per 64-node partition
    dim3 gGemm((N + 63) / 64);
    dim3 gWave((N + 3) / 4);

    k_pre<<<gPre, blk, 0, stream>>>(tail, NP, W0, W1, W2, wt0, wt1, wt2);
    k_bin<<<gBin, blk, 0, stream>>>(src, dst, ew, tail, glist, E, ecap, NP, shift);
    k_fill<<<gFill, blk, 0, stream>>>(tail, glist, ecap, cnt, dinv, EW, cap, N, shift);

    // layer 0 (x fp32 -> cvt in-kernel)
    k_gemm<128, true><<<gGemm, blk, 0, stream>>>(x, wt0, dinv, bufH, N);
    k_agg<128, true><<<gWave, blk, 0, stream>>>(bufH, EW, cnt, dinv, b0, bufA, N, cap);

    // layer 1
    k_gemm<128, false><<<gGemm, blk, 0, stream>>>(bufA, wt1, dinv, bufH, N);
    k_agg<128, true><<<gWave, blk, 0, stream>>>(bufH, EW, cnt, dinv, b1, bufA, N, cap);

    // layer 2 (no relu, fp32 out)
    k_gemm<64, false><<<gGemm, blk, 0, stream>>>(bufA, wt2, dinv, bufH, N);
    k_agg<64, false><<<gWave, blk, 0, stream>>>(bufH, EW, cnt, dinv, b2,
                                                d_out, N, cap);
}